// Round 7
// baseline (211.341 us; speedup 1.0000x reference)
//
#include <hip/hip_runtime.h>
#include <math.h>

#define CRF_B 256
#define CRF_S 2048
#define CRF_K 64
#define NSEG 64
#define SEGL 32
#define BURN 8
#define DEPTH 40  // BURN + 32 accumulation steps

typedef short bf16x8 __attribute__((ext_vector_type(8)));  // 8 bf16 = 4 VGPRs
typedef float f32x4 __attribute__((ext_vector_type(4)));
typedef __attribute__((address_space(3))) void lds_void;
typedef const __attribute__((address_space(1))) void glb_void;

// Compiler-only fence; per-wave DS ops are processed in-order by the LDS pipe
// (write->read visibility verified across prior rounds, absmax 0).
__device__ __forceinline__ void lds_fence() { asm volatile("" ::: "memory"); }

__device__ __forceinline__ unsigned bf16rne(float x) {
    unsigned u = __float_as_uint(x);
    return (u + 0x7FFFu + ((u >> 16) & 1u)) >> 16;
}
// trunc-bf16 pack of (x,y) via one v_perm_b32 (validated earlier, absmax 0).
__device__ __forceinline__ unsigned pktrunc(float x, float y) {
    return __builtin_amdgcn_perm(__float_as_uint(y), __float_as_uint(x), 0x07060302u);
}
__device__ __forceinline__ int expOf(float m) {  // e such that m*2^-e in [0.5,1)
    return ((__float_as_int(m) >> 23) & 255) - 126;
}

// Round 7: round-6 structure (SEGL=32, BURN=8, 256 blocks x 4 waves) with the
// emission DMA pipeline deepened 2 -> 4 slots. At 1 wave/SIMD the 2-slot
// pipeline left only ~16 KB/wave in flight and BW fell to 1.45 TB/s
// (concurrency-limited); 4 slots restores 32 KB/wave (32 MB device-wide,
// matching the 8-wave/CU configs that saturated ~2.2 TB/s). Steady-state
// wait vmcnt(24) (3 newer slots stay in flight), tail ramp 16/8/0. All
// numerics identical to round 6 (absmax 0 there).
__global__ __launch_bounds__(256, 1) void crf_scan(
    const float* __restrict__ scores, const int* __restrict__ states,
    const float* __restrict__ trans, const float* __restrict__ source,
    const float* __restrict__ sink, float* __restrict__ lossOut)
{
    const int tid = threadIdx.x;
    const int lane = tid & 63;
    const int w = tid >> 6;        // wave 0..3
    const int b = blockIdx.x;
    const int c = lane & 15;       // chain-within-wave
    const int q = lane >> 4;       // quad
    const int sg = w * 16 + c;     // global segment id 0..63

    __shared__ __align__(16) short Pbuf[4][16 * 72];   // per-wave [chain][state], stride 72
    __shared__ __align__(16) float Ebuf[4][4 * 2048];  // per-wave 4-slot DMA buffer (4 x 8 KB)
    __shared__ float sC[NSEG];
    __shared__ float gW[4];
    __shared__ float dotSh;
    short* myP = Pbuf[w];
    float* myE = Ebuf[w];

    const float* scb = scores + (size_t)b * CRF_S * CRF_K;

    // ---------- gold-path partial (this wave's 1/4 of the sequence) ----------
    {
        const int* st = states + b * CRF_S;
        float g = 0.f;
#pragma unroll
        for (int it = 0; it < 8; ++it) {
            int p = w * 512 + it * 64 + lane;
            int cur = st[p];
            g += scb[(size_t)p * CRF_K + cur];
            if (p > 0) g += trans[st[p - 1] * CRF_K + cur];
            if (p == 0) g += source[cur];
            if (p == CRF_S - 1) g += sink[cur];
        }
#pragma unroll
        for (int m = 32; m >= 1; m >>= 1) g += __shfl_xor(g, m, 64);
        if (lane == 0) gW[w] = g;
    }

    // ---------- static E fragments (A operand), bf16 RNE ----------
    bf16x8 Af[4][2];
#pragma unroll
    for (int g4 = 0; g4 < 4; ++g4)
#pragma unroll
        for (int h = 0; h < 2; ++h) {
            bf16x8 t;
#pragma unroll
            for (int jv = 0; jv < 8; ++jv)
                t[jv] = (short)bf16rne(__expf(trans[(h * 32 + q * 8 + jv) * CRF_K + g4 * 16 + c]));
            Af[g4][h] = t;
        }

    // exact init for chain 0: exp(source + scores[b][0][:]) (layout depends on q only)
    float ini[16];
#pragma unroll
    for (int i = 0; i < 16; ++i) {
        int st8 = 16 * (i >> 2) + 4 * q + (i & 3);
        ini[i] = __expf(source[st8] + scb[st8]);
    }

    // P init: ones (bf16 1.0 = 0x3F80)
#pragma unroll
    for (int g4 = 0; g4 < 4; ++g4)
        *(int2*)(myP + c * 72 + 16 * g4 + 4 * q) =
            make_int2((int)0x3F803F80u, (int)0x3F803F80u);
    lds_fence();
    bf16x8 bf0 = *(const bf16x8*)(myP + c * 72 + q * 8);
    bf16x8 bf1 = *(const bf16x8*)(myP + c * 72 + 32 + q * 8);

    // ---------- emission DMA pipeline (2 rows/chain per touch, 4 slots) ----------
    // Instruction j (j=0..7): lanes 0-31 -> chain 2j, lanes 32-63 -> chain 2j+1;
    // within a chain-half, p_=(lane>>4)&1 selects row k0+p_, m_=lane&15 the 16 B
    // unit (source-swizzled by ^chain). LDS dest per instr: linear 1 KB.
    const int m_ = lane & 15;
    const int p_ = (lane >> 4) & 1;
    const int hi = lane >> 5;
    int rbase[8], uoff[8];
#pragma unroll
    for (int j = 0; j < 8; ++j) {
        int ch = 2 * j + hi;
        rbase[j] = (w * 16 + ch) * SEGL - BURN + p_;
        uoff[j] = ((m_ ^ ch) & 15) * 4;  // floats
    }
    auto issue2 = [&](int k0) {  // rows k0,k0+1 for all 16 chains -> slot (k0>>1)&3
        const int sl = (k0 >> 1) & 3;
#pragma unroll
        for (int j = 0; j < 8; ++j) {
            int t = min(max(rbase[j] + k0, 0), CRF_S - 1);
            const float* g = scb + (size_t)t * CRF_K + uoff[j];
            float* l = myE + sl * 2048 + j * 256;
            __builtin_amdgcn_global_load_lds((glb_void*)g, (lds_void*)l, 16, 0, 0);
        }
    };
    issue2(0);  // steps {0,1} -> slot 0
    issue2(2);  // steps {2,3} -> slot 1
    issue2(4);  // steps {4,5} -> slot 2
    issue2(6);  // steps {6,7} -> slot 3

    float v[16];
    int cint = 0, e_pend = 0;

    for (int kk = 0; kk < DEPTH; kk += 4) {
#pragma unroll
        for (int ph = 0; ph < 4; ++ph) {
            const int k = kk + ph;
            // (1) even step: retire this slot's 8 DMAs. Steady state keeps the
            // 3 newer slots (24 DMAs) in flight; tail ramps down as refills
            // stop (last refill issues pair {DEPTH-2,DEPTH-1} at k=DEPTH-9).
            if ((ph & 1) == 0) {
                if (k == DEPTH - 2)      asm volatile("s_waitcnt vmcnt(0)"  ::: "memory");
                else if (k == DEPTH - 4) asm volatile("s_waitcnt vmcnt(8)"  ::: "memory");
                else if (k == DEPTH - 6) asm volatile("s_waitcnt vmcnt(16)" ::: "memory");
                else                     asm volatile("s_waitcnt vmcnt(24)" ::: "memory");
            }
            // read es slices: chain c block (512 B), row parity k&1, swizzled unit
            const float* eb = myE + ((k >> 1) & 3) * 2048 + c * 128 + (k & 1) * 64;
            float4 sl4[4];
#pragma unroll
            for (int g4 = 0; g4 < 4; ++g4)
                sl4[g4] = *(const float4*)(eb + (((4 * g4 + q) ^ c) << 2));
            // odd step: slot fully consumed; close WAR window, refill with the
            // pair 4 slots ahead (steps k+7,k+8). Guard: skip never-consumed.
            if ((ph & 1) && (k + 7 < DEPTH)) {
                asm volatile("s_waitcnt lgkmcnt(0)" ::: "memory");
                issue2(k + 7);
            }
            float es[16];
#pragma unroll
            for (int g4 = 0; g4 < 4; ++g4) {
                es[g4 * 4 + 0] = __expf(sl4[g4].x);
                es[g4 * 4 + 1] = __expf(sl4[g4].y);
                es[g4 * 4 + 2] = __expf(sl4[g4].z);
                es[g4 * 4 + 3] = __expf(sl4[g4].w);
            }
            // (2) MFMA: D[state][chain]
            f32x4 acc[4];
#pragma unroll
            for (int g4 = 0; g4 < 4; ++g4) {
                f32x4 z = {0.f, 0.f, 0.f, 0.f};
                z = __builtin_amdgcn_mfma_f32_16x16x32_bf16(Af[g4][0], bf0, z, 0, 0, 0);
                z = __builtin_amdgcn_mfma_f32_16x16x32_bf16(Af[g4][1], bf1, z, 0, 0, 0);
                acc[g4] = z;
            }
            // (3) v = acc*es, applying the pending strip on period boundaries
            if (ph == 0) {
                const float s2 = ldexpf(1.0f, -e_pend);
                cint += e_pend;
#pragma unroll
                for (int i = 0; i < 16; ++i) v[i] = acc[i >> 2][i & 3] * es[i] * s2;
            } else {
#pragma unroll
                for (int i = 0; i < 16; ++i) v[i] = acc[i >> 2][i & 3] * es[i];
            }
            // (4a) end-of-burn canonical strip (all chains), reset bookkeeping
            if (k == BURN - 1) {
                float mc = v[0];
#pragma unroll
                for (int i = 1; i < 16; ++i) mc = fmaxf(mc, v[i]);
                mc = fmaxf(mc, __shfl_xor(mc, 16, 64));
                mc = fmaxf(mc, __shfl_xor(mc, 32, 64));
                const float sc2 = ldexpf(1.0f, -expOf(mc));
#pragma unroll
                for (int i = 0; i < 16; ++i) v[i] *= sc2;
                cint = 0;
                e_pend = 0;
            }
            // (4b) chain-0 exact injection (its t=0 "step" result is discarded)
            if (k == BURN) {
                if (sg == 0) {
#pragma unroll
                    for (int i = 0; i < 16; ++i) v[i] = ini[i];
                }
                float mc = v[0];
#pragma unroll
                for (int i = 1; i < 16; ++i) mc = fmaxf(mc, v[i]);
                mc = fmaxf(mc, __shfl_xor(mc, 16, 64));
                mc = fmaxf(mc, __shfl_xor(mc, 32, 64));
                const int ec = expOf(mc);
                if (sg == 0) {
                    const float sc2 = ldexpf(1.0f, -ec);
#pragma unroll
                    for (int i = 0; i < 16; ++i) v[i] *= sc2;
                    cint = ec;
                }
            }
            // (5) periodic strip compute (stale-by-1-step; applied at next ph==0)
            if (ph == 3 && k != BURN - 1) {
                float mx = v[0];
#pragma unroll
                for (int i = 1; i < 16; ++i) mx = fmaxf(mx, v[i]);
                mx = fmaxf(mx, __shfl_xor(mx, 16, 64));
                mx = fmaxf(mx, __shfl_xor(mx, 32, 64));
                e_pend = expOf(mx);
            }
            // (6) pack (trunc) + write own chain's 16 states; read next B frags
#pragma unroll
            for (int g4 = 0; g4 < 4; ++g4) {
                unsigned lo = pktrunc(v[g4 * 4 + 0], v[g4 * 4 + 1]);
                unsigned hi2 = pktrunc(v[g4 * 4 + 2], v[g4 * 4 + 3]);
                *(int2*)(myP + c * 72 + 16 * g4 + 4 * q) = make_int2((int)lo, (int)hi2);
            }
            lds_fence();
            bf0 = *(const bf16x8*)(myP + c * 72 + q * 8);
            bf1 = *(const bf16x8*)(myP + c * 72 + 32 + q * 8);
        }
    }

    // final canonical strip (telescopes with next segment's burn-in canonical)
    float mf = v[0];
#pragma unroll
    for (int i = 1; i < 16; ++i) mf = fmaxf(mf, v[i]);
    mf = fmaxf(mf, __shfl_xor(mf, 16, 64));
    mf = fmaxf(mf, __shfl_xor(mf, 32, 64));
    const int ef = expOf(mf);
    cint += ef;
    const float sf = ldexpf(1.0f, -ef);

    // ---------- fused per-batch epilogue ----------
    if (q == 0) sC[sg] = (float)cint * 0.6931471805599453f;
    if (w == 3) {
        // chain 63 lanes: dot(vlast, exp(sink))
        float pd = 0.f;
        if (c == 15) {
#pragma unroll
            for (int i = 0; i < 16; ++i) {
                int st8 = 16 * (i >> 2) + 4 * q + (i & 3);
                pd += v[i] * sf * __expf(sink[st8]);
            }
        }
        pd += __shfl_xor(pd, 16, 64);
        pd += __shfl_xor(pd, 32, 64);
        if (lane == 15) dotSh = pd;
    }
    __syncthreads();
    if (w == 0) {
        float t2 = sC[lane & 63];
#pragma unroll
        for (int m = 32; m >= 1; m >>= 1) t2 += __shfl_xor(t2, m, 64);
        if (lane == 0) {
            float gold = gW[0] + gW[1] + gW[2] + gW[3];
            lossOut[b] = t2 + logf(dotSh) - gold;
        }
    }
}

__global__ __launch_bounds__(256) void crf_finish(
    const float* __restrict__ loss, float* __restrict__ out)
{
    const int bt = threadIdx.x;
    __shared__ float red[256];
    red[bt] = loss[bt];
    __syncthreads();
    for (int s2 = 128; s2 > 0; s2 >>= 1) {
        if (bt < s2) red[bt] += red[bt + s2];
        __syncthreads();
    }
    if (bt == 0) out[0] = red[0] * (1.0f / CRF_B);
}

extern "C" void kernel_launch(void* const* d_in, const int* in_sizes, int n_in,
                              void* d_out, int out_size, void* d_ws, size_t ws_size,
                              hipStream_t stream) {
    const float* scores = (const float*)d_in[0];
    const int*   states = (const int*)d_in[1];
    const float* trans  = (const float*)d_in[2];
    const float* source = (const float*)d_in[3];
    const float* sink   = (const float*)d_in[4];

    float* loss = (float*)d_ws;   // 256 per-batch losses
    float* out = (float*)d_out;

    crf_scan<<<CRF_B, 256, 0, stream>>>(scores, states, trans, source, sink, loss);
    crf_finish<<<1, 256, 0, stream>>>(loss, out);
}

// Round 8
// 208.562 us; speedup vs baseline: 1.0133x; 1.0133x over previous
//
#include <hip/hip_runtime.h>
#include <math.h>

#define CRF_B 256
#define CRF_S 2048
#define CRF_K 64
#define NSEG 64
#define SEGL 32
#define BURN 4
#define DEPTH 36  // BURN + 32 accumulation steps

typedef short bf16x8 __attribute__((ext_vector_type(8)));  // 8 bf16 = 4 VGPRs
typedef float f32x4 __attribute__((ext_vector_type(4)));
typedef __attribute__((address_space(3))) void lds_void;
typedef const __attribute__((address_space(1))) void glb_void;

// Compiler-only fence; per-wave DS ops are processed in-order by the LDS pipe
// (write->read visibility verified across prior rounds, absmax 0).
__device__ __forceinline__ void lds_fence() { asm volatile("" ::: "memory"); }

__device__ __forceinline__ unsigned bf16rne(float x) {
    unsigned u = __float_as_uint(x);
    return (u + 0x7FFFu + ((u >> 16) & 1u)) >> 16;
}
// trunc-bf16 pack of (x,y) via one v_perm_b32 (validated earlier, absmax 0).
__device__ __forceinline__ unsigned pktrunc(float x, float y) {
    return __builtin_amdgcn_perm(__float_as_uint(y), __float_as_uint(x), 0x07060302u);
}
__device__ __forceinline__ int expOf(float m) {  // e such that m*2^-e in [0.5,1)
    return ((__float_as_int(m) >> 23) & 255) - 126;
}

// Round 8: R6 structure (SEGL=32, 2-slot DMA double buffer, 256 blocks x 4
// waves) with BURN 8 -> 4 (DEPTH 36). Cross-round fit shows the score tracks
// scan FETCH bytes (~0.19 us/MB) because the harness poison-fills dominate
// the bus; BURN=4 cuts raw demand 168 -> 151 MB and steps -10%. Burn-in only
// needs to converge the handoff direction to the bf16 noise floor of the P
// store (~0.4%), which BURN16->8's absmax-0 transition bounds as reached by
// ~4 steps. Also: first DMA slots issue BEFORE the gold-path prologue so
// pipeline fill hides under prologue work (vmcnt in-order; gold's own waits
// simply drain them early - harmless).
__global__ __launch_bounds__(256, 2) void crf_scan(
    const float* __restrict__ scores, const int* __restrict__ states,
    const float* __restrict__ trans, const float* __restrict__ source,
    const float* __restrict__ sink, float* __restrict__ lossOut)
{
    const int tid = threadIdx.x;
    const int lane = tid & 63;
    const int w = tid >> 6;        // wave 0..3
    const int b = blockIdx.x;
    const int c = lane & 15;       // chain-within-wave
    const int q = lane >> 4;       // quad
    const int sg = w * 16 + c;     // global segment id 0..63

    __shared__ __align__(16) short Pbuf[4][16 * 72];   // per-wave [chain][state], stride 72
    __shared__ __align__(16) float Ebuf[4][2 * 2048];  // per-wave 2-slot DMA buffer (2 x 8 KB)
    __shared__ float sC[NSEG];
    __shared__ float gW[4];
    __shared__ float dotSh;
    short* myP = Pbuf[w];
    float* myE = Ebuf[w];

    const float* scb = scores + (size_t)b * CRF_S * CRF_K;

    // ---------- emission DMA pipeline setup + first issues (moved to top) ----------
    // Instruction j (j=0..7): lanes 0-31 -> chain 2j, lanes 32-63 -> chain 2j+1;
    // within a chain-half, p_=(lane>>4)&1 selects row k0+p_, m_=lane&15 the 16 B
    // unit (source-swizzled by ^chain). LDS dest per instr: linear 1 KB.
    const int m_ = lane & 15;
    const int p_ = (lane >> 4) & 1;
    const int hi = lane >> 5;
    int rbase[8], uoff[8];
#pragma unroll
    for (int j = 0; j < 8; ++j) {
        int ch = 2 * j + hi;
        rbase[j] = (w * 16 + ch) * SEGL - BURN + p_;
        uoff[j] = ((m_ ^ ch) & 15) * 4;  // floats
    }
    auto issue2 = [&](int k0) {  // rows k0,k0+1 for all 16 chains -> slot (k0>>1)&1
        const int sl = (k0 >> 1) & 1;
#pragma unroll
        for (int j = 0; j < 8; ++j) {
            int t = min(max(rbase[j] + k0, 0), CRF_S - 1);
            const float* g = scb + (size_t)t * CRF_K + uoff[j];
            float* l = myE + sl * 2048 + j * 256;
            __builtin_amdgcn_global_load_lds((glb_void*)g, (lds_void*)l, 16, 0, 0);
        }
    };
    issue2(0);  // steps {0,1} -> slot 0
    issue2(2);  // steps {2,3} -> slot 1

    // ---------- gold-path partial (this wave's 1/4 of the sequence) ----------
    {
        const int* st = states + b * CRF_S;
        float g = 0.f;
#pragma unroll
        for (int it = 0; it < 8; ++it) {
            int p = w * 512 + it * 64 + lane;
            int cur = st[p];
            g += scb[(size_t)p * CRF_K + cur];
            if (p > 0) g += trans[st[p - 1] * CRF_K + cur];
            if (p == 0) g += source[cur];
            if (p == CRF_S - 1) g += sink[cur];
        }
#pragma unroll
        for (int m = 32; m >= 1; m >>= 1) g += __shfl_xor(g, m, 64);
        if (lane == 0) gW[w] = g;
    }

    // ---------- static E fragments (A operand), bf16 RNE ----------
    bf16x8 Af[4][2];
#pragma unroll
    for (int g4 = 0; g4 < 4; ++g4)
#pragma unroll
        for (int h = 0; h < 2; ++h) {
            bf16x8 t;
#pragma unroll
            for (int jv = 0; jv < 8; ++jv)
                t[jv] = (short)bf16rne(__expf(trans[(h * 32 + q * 8 + jv) * CRF_K + g4 * 16 + c]));
            Af[g4][h] = t;
        }

    // exact init for chain 0: exp(source + scores[b][0][:]) (layout depends on q only)
    float ini[16];
#pragma unroll
    for (int i = 0; i < 16; ++i) {
        int st8 = 16 * (i >> 2) + 4 * q + (i & 3);
        ini[i] = __expf(source[st8] + scb[st8]);
    }

    // P init: ones (bf16 1.0 = 0x3F80)
#pragma unroll
    for (int g4 = 0; g4 < 4; ++g4)
        *(int2*)(myP + c * 72 + 16 * g4 + 4 * q) =
            make_int2((int)0x3F803F80u, (int)0x3F803F80u);
    lds_fence();
    bf16x8 bf0 = *(const bf16x8*)(myP + c * 72 + q * 8);
    bf16x8 bf1 = *(const bf16x8*)(myP + c * 72 + 32 + q * 8);

    float v[16];
    int cint = 0, e_pend = 0;

    for (int kk = 0; kk < DEPTH; kk += 4) {
#pragma unroll
        for (int ph = 0; ph < 4; ++ph) {
            const int k = kk + ph;
            // (1) even step: retire this slot's 8 DMAs. Normally 8 newer stay
            // in flight; for the last slot (k == DEPTH-2) no newer fills were
            // issued (guard below), so drain fully.
            if ((ph & 1) == 0) {
                if (k == DEPTH - 2) asm volatile("s_waitcnt vmcnt(0)" ::: "memory");
                else                asm volatile("s_waitcnt vmcnt(8)" ::: "memory");
            }
            // read es slices: chain c block (512 B), row parity k&1, swizzled unit
            const float* eb = myE + ((k >> 1) & 1) * 2048 + c * 128 + (k & 1) * 64;
            float4 sl4[4];
#pragma unroll
            for (int g4 = 0; g4 < 4; ++g4)
                sl4[g4] = *(const float4*)(eb + (((4 * g4 + q) ^ c) << 2));
            // odd step: slot fully consumed; close WAR window, refill for k+3,k+4.
            // Guard: skip fills whose steps are never consumed (k+3 >= DEPTH).
            if ((ph & 1) && (k + 3 < DEPTH)) {
                asm volatile("s_waitcnt lgkmcnt(0)" ::: "memory");
                issue2(k + 3);
            }
            float es[16];
#pragma unroll
            for (int g4 = 0; g4 < 4; ++g4) {
                es[g4 * 4 + 0] = __expf(sl4[g4].x);
                es[g4 * 4 + 1] = __expf(sl4[g4].y);
                es[g4 * 4 + 2] = __expf(sl4[g4].z);
                es[g4 * 4 + 3] = __expf(sl4[g4].w);
            }
            // (2) MFMA: D[state][chain]
            f32x4 acc[4];
#pragma unroll
            for (int g4 = 0; g4 < 4; ++g4) {
                f32x4 z = {0.f, 0.f, 0.f, 0.f};
                z = __builtin_amdgcn_mfma_f32_16x16x32_bf16(Af[g4][0], bf0, z, 0, 0, 0);
                z = __builtin_amdgcn_mfma_f32_16x16x32_bf16(Af[g4][1], bf1, z, 0, 0, 0);
                acc[g4] = z;
            }
            // (3) v = acc*es, applying the pending strip on period boundaries
            if (ph == 0) {
                const float s2 = ldexpf(1.0f, -e_pend);
                cint += e_pend;
#pragma unroll
                for (int i = 0; i < 16; ++i) v[i] = acc[i >> 2][i & 3] * es[i] * s2;
            } else {
#pragma unroll
                for (int i = 0; i < 16; ++i) v[i] = acc[i >> 2][i & 3] * es[i];
            }
            // (4a) end-of-burn canonical strip (all chains), reset bookkeeping
            // (BURN-1 = 3 falls on ph==3, replacing that period's strip (5)).
            if (k == BURN - 1) {
                float mc = v[0];
#pragma unroll
                for (int i = 1; i < 16; ++i) mc = fmaxf(mc, v[i]);
                mc = fmaxf(mc, __shfl_xor(mc, 16, 64));
                mc = fmaxf(mc, __shfl_xor(mc, 32, 64));
                const float sc2 = ldexpf(1.0f, -expOf(mc));
#pragma unroll
                for (int i = 0; i < 16; ++i) v[i] *= sc2;
                cint = 0;
                e_pend = 0;
            }
            // (4b) chain-0 exact injection (its computed t=0 "step" result is
            // discarded; BURN = 4 falls on ph==0, after (3) applied e_pend=0).
            if (k == BURN) {
                if (sg == 0) {
#pragma unroll
                    for (int i = 0; i < 16; ++i) v[i] = ini[i];
                }
                float mc = v[0];
#pragma unroll
                for (int i = 1; i < 16; ++i) mc = fmaxf(mc, v[i]);
                mc = fmaxf(mc, __shfl_xor(mc, 16, 64));
                mc = fmaxf(mc, __shfl_xor(mc, 32, 64));
                const int ec = expOf(mc);
                if (sg == 0) {
                    const float sc2 = ldexpf(1.0f, -ec);
#pragma unroll
                    for (int i = 0; i < 16; ++i) v[i] *= sc2;
                    cint = ec;
                }
            }
            // (5) periodic strip compute (stale-by-1-step; applied at next ph==0)
            if (ph == 3 && k != BURN - 1) {
                float mx = v[0];
#pragma unroll
                for (int i = 1; i < 16; ++i) mx = fmaxf(mx, v[i]);
                mx = fmaxf(mx, __shfl_xor(mx, 16, 64));
                mx = fmaxf(mx, __shfl_xor(mx, 32, 64));
                e_pend = expOf(mx);
            }
            // (6) pack (trunc) + write own chain's 16 states; read next B frags
#pragma unroll
            for (int g4 = 0; g4 < 4; ++g4) {
                unsigned lo = pktrunc(v[g4 * 4 + 0], v[g4 * 4 + 1]);
                unsigned hi2 = pktrunc(v[g4 * 4 + 2], v[g4 * 4 + 3]);
                *(int2*)(myP + c * 72 + 16 * g4 + 4 * q) = make_int2((int)lo, (int)hi2);
            }
            lds_fence();
            bf0 = *(const bf16x8*)(myP + c * 72 + q * 8);
            bf1 = *(const bf16x8*)(myP + c * 72 + 32 + q * 8);
        }
    }

    // final canonical strip (telescopes with next segment's burn-in canonical)
    float mf = v[0];
#pragma unroll
    for (int i = 1; i < 16; ++i) mf = fmaxf(mf, v[i]);
    mf = fmaxf(mf, __shfl_xor(mf, 16, 64));
    mf = fmaxf(mf, __shfl_xor(mf, 32, 64));
    const int ef = expOf(mf);
    cint += ef;
    const float sf = ldexpf(1.0f, -ef);

    // ---------- fused per-batch epilogue ----------
    if (q == 0) sC[sg] = (float)cint * 0.6931471805599453f;
    if (w == 3) {
        // chain 63 lanes: dot(vlast, exp(sink))
        float pd = 0.f;
        if (c == 15) {
#pragma unroll
            for (int i = 0; i < 16; ++i) {
                int st8 = 16 * (i >> 2) + 4 * q + (i & 3);
                pd += v[i] * sf * __expf(sink[st8]);
            }
        }
        pd += __shfl_xor(pd, 16, 64);
        pd += __shfl_xor(pd, 32, 64);
        if (lane == 15) dotSh = pd;
    }
    __syncthreads();
    if (w == 0) {
        float t2 = sC[lane & 63];
#pragma unroll
        for (int m = 32; m >= 1; m >>= 1) t2 += __shfl_xor(t2, m, 64);
        if (lane == 0) {
            float gold = gW[0] + gW[1] + gW[2] + gW[3];
            lossOut[b] = t2 + logf(dotSh) - gold;
        }
    }
}

__global__ __launch_bounds__(256) void crf_finish(
    const float* __restrict__ loss, float* __restrict__ out)
{
    const int bt = threadIdx.x;
    __shared__ float red[256];
    red[bt] = loss[bt];
    __syncthreads();
    for (int s2 = 128; s2 > 0; s2 >>= 1) {
        if (bt < s2) red[bt] += red[bt + s2];
        __syncthreads();
    }
    if (bt == 0) out[0] = red[0] * (1.0f / CRF_B);
}

extern "C" void kernel_launch(void* const* d_in, const int* in_sizes, int n_in,
                              void* d_out, int out_size, void* d_ws, size_t ws_size,
                              hipStream_t stream) {
    const float* scores = (const float*)d_in[0];
    const int*   states = (const int*)d_in[1];
    const float* trans  = (const float*)d_in[2];
    const float* source = (const float*)d_in[3];
    const float* sink   = (const float*)d_in[4];

    float* loss = (float*)d_ws;   // 256 per-batch losses
    float* out = (float*)d_out;

    crf_scan<<<CRF_B, 256, 0, stream>>>(scores, states, trans, source, sink, loss);
    crf_finish<<<1, 256, 0, stream>>>(loss, out);
}